// Round 1
// baseline (103.023 us; speedup 1.0000x reference)
//
#include <hip/hip_runtime.h>

// Embedding gather with per-row dequant:
//   out[token, :] = float(weight[x[token], :]) * scaler[x[token]]
// V=128000, D=2048, tokens = B*S = 4*8192 = 32768.
// weight is int32 (int8-range values), scaler f32, out f32.
//
// One block (256 threads) per token: 2048 elems = 512 int4 loads = 256 threads x 2.
// 16B/lane loads+stores, fully coalesced. Memory-bound by design.

#define D_EMB 2048

__global__ __launch_bounds__(256) void embed_dequant_gather(
    const int* __restrict__ x,
    const int* __restrict__ weight,
    const float* __restrict__ scaler,
    float* __restrict__ out,
    int n_tokens)
{
    const int token = blockIdx.x;
    if (token >= n_tokens) return;

    // Wave-uniform row index + scale (broadcast from cache).
    const int row = x[token];
    const float s = scaler[row];

    const int4* __restrict__ wrow =
        reinterpret_cast<const int4*>(weight + (size_t)row * D_EMB);
    float4* __restrict__ orow =
        reinterpret_cast<float4*>(out + (size_t)token * D_EMB);

    const int t = threadIdx.x;
    #pragma unroll
    for (int i = 0; i < 2; ++i) {
        const int4 w = wrow[t + i * 256];
        float4 o;
        o.x = (float)w.x * s;
        o.y = (float)w.y * s;
        o.z = (float)w.z * s;
        o.w = (float)w.w * s;
        orow[t + i * 256] = o;
    }
}

extern "C" void kernel_launch(void* const* d_in, const int* in_sizes, int n_in,
                              void* d_out, int out_size, void* d_ws, size_t ws_size,
                              hipStream_t stream) {
    const int*   x      = (const int*)d_in[0];        // [B*S] indices
    const int*   weight = (const int*)d_in[1];        // [V, D] int32 (int8-range)
    const float* scaler = (const float*)d_in[2];      // [V]
    float*       out    = (float*)d_out;              // [B*S, D] f32

    const int n_tokens = in_sizes[0];                 // 32768

    dim3 grid(n_tokens);
    dim3 block(256);
    embed_dequant_gather<<<grid, block, 0, stream>>>(x, weight, scaler, out, n_tokens);
}

// Round 3
// 80.308 us; speedup vs baseline: 1.2829x; 1.2829x over previous
//
#include <hip/hip_runtime.h>

// Embedding gather with per-row dequant:
//   out[token, :] = float(weight[x[token], :]) * scaler[x[token]]
// V=128000, D=2048, tokens = B*S = 4*8192 = 32768.
// weight is int32 (int8-range values), scaler f32, out f32.
//
// One block (256 threads) per token: 2048 elems = 512 int4 loads = 256 threads x 2.
// 16B/lane loads+stores, fully coalesced.
// R3: output stores are NON-TEMPORAL (via clang ext_vector_type, since the
// builtin rejects HIP_vector_type float4) — out is write-once, never re-read;
// keeping it out of L2/L3 leaves the 256MiB Infinity Cache free to hold the
// ~232MiB unique-row working set of the table, so duplicate-row reads hit L3.

#define D_EMB 2048

typedef float  fx4 __attribute__((ext_vector_type(4)));
typedef int    ix4 __attribute__((ext_vector_type(4)));

__global__ __launch_bounds__(256) void embed_dequant_gather(
    const int* __restrict__ x,
    const int* __restrict__ weight,
    const float* __restrict__ scaler,
    float* __restrict__ out,
    int n_tokens)
{
    const int token = blockIdx.x;
    if (token >= n_tokens) return;

    // Wave-uniform row index + scale (broadcast from cache).
    const int row = x[token];
    const float s = scaler[row];

    const ix4* __restrict__ wrow =
        reinterpret_cast<const ix4*>(weight + (size_t)row * D_EMB);
    fx4* __restrict__ orow =
        reinterpret_cast<fx4*>(out + (size_t)token * D_EMB);

    const int t = threadIdx.x;
    #pragma unroll
    for (int i = 0; i < 2; ++i) {
        const ix4 w = wrow[t + i * 256];
        fx4 o;
        o.x = (float)w.x * s;
        o.y = (float)w.y * s;
        o.z = (float)w.z * s;
        o.w = (float)w.w * s;
        __builtin_nontemporal_store(o, &orow[t + i * 256]);
    }
}

extern "C" void kernel_launch(void* const* d_in, const int* in_sizes, int n_in,
                              void* d_out, int out_size, void* d_ws, size_t ws_size,
                              hipStream_t stream) {
    const int*   x      = (const int*)d_in[0];        // [B*S] indices
    const int*   weight = (const int*)d_in[1];        // [V, D] int32 (int8-range)
    const float* scaler = (const float*)d_in[2];      // [V]
    float*       out    = (float*)d_out;              // [B*S, D] f32

    const int n_tokens = in_sizes[0];                 // 32768

    dim3 grid(n_tokens);
    dim3 block(256);
    embed_dequant_gather<<<grid, block, 0, stream>>>(x, weight, scaler, out, n_tokens);
}